// Round 10
// baseline (393.351 us; speedup 1.0000x reference)
//
#include <hip/hip_runtime.h>
#include <math.h>

#define HW 1024
#define CDIM 384
#define NB 32
#define MTOT (NB * HW)
#define EPS 1e-5f

typedef unsigned short u16;
typedef short s8v __attribute__((ext_vector_type(8)));
typedef float f4v __attribute__((ext_vector_type(4)));
typedef _Float16 h2v __attribute__((ext_vector_type(2)));
typedef _Float16 h8v __attribute__((ext_vector_type(8)));

union U8 { s8v v; u16 u[8]; };

__device__ __forceinline__ float bf2f(u16 u) {
  union { float f; unsigned int i; } x; x.i = ((unsigned int)u) << 16; return x.f;
}
__device__ __forceinline__ u16 f2bf(float f) {
  union { float f; unsigned int i; } x; x.f = f;
  unsigned int r = (x.i + 0x7FFFu + ((x.i >> 16) & 1u)) >> 16;
  return (u16)r;
}
__device__ __forceinline__ float gelu_exact(float v) {
  return 0.5f * v * (1.f + erff(v * 0.70710678118654752f));
}

// async global->LDS, 16B per lane; LDS dest = wave-uniform base + lane*16
__device__ __forceinline__ void gload16(const u16* g, u16* l) {
  __builtin_amdgcn_global_load_lds(
      (const __attribute__((address_space(1))) unsigned int*)(unsigned long long)(const void*)g,
      (__attribute__((address_space(3))) unsigned int*)(unsigned int)(unsigned long long)(void*)l,
      16, 0, 0);
}

// ---------------- LN1 stats, two-stage ----------------
__global__ __launch_bounds__(256) void k_statsA(const float* __restrict__ x,
                                                float* __restrict__ part) {
  int blk = blockIdx.x;
  const float4* xb = (const float4*)(x + (size_t)blk * 12288);
  float s = 0.f, s2 = 0.f;
  for (int i = threadIdx.x; i < 3072; i += 256) {
    float4 v = xb[i];
    s += v.x + v.y + v.z + v.w;
    s2 += v.x * v.x + v.y * v.y + v.z * v.z + v.w * v.w;
  }
  __shared__ float ls[256], ls2[256];
  ls[threadIdx.x] = s; ls2[threadIdx.x] = s2;
  __syncthreads();
  for (int off = 128; off > 0; off >>= 1) {
    if (threadIdx.x < off) {
      ls[threadIdx.x] += ls[threadIdx.x + off];
      ls2[threadIdx.x] += ls2[threadIdx.x + off];
    }
    __syncthreads();
  }
  if (threadIdx.x == 0) { part[blk * 2] = ls[0]; part[blk * 2 + 1] = ls2[0]; }
}

__global__ void k_statsB(const float* __restrict__ part, float* __restrict__ stats) {
  int b = threadIdx.x;
  if (b >= 32) return;
  float s = 0.f, s2 = 0.f;
  for (int i = 0; i < 32; i++) {
    s += part[(b * 32 + i) * 2];
    s2 += part[(b * 32 + i) * 2 + 1];
  }
  const float inv_n = 1.f / (CDIM * HW);
  float m = s * inv_n;
  stats[b] = m;
  stats[32 + b] = rsqrtf(s2 * inv_n - m * m + EPS);
}

// ---------------- weight f32->bf16 conversion ----------------
__global__ __launch_bounds__(256) void k_cvtwE(const float* __restrict__ piw,
                                               const float* __restrict__ pow_,
                                               const float* __restrict__ p0w,
                                               const float* __restrict__ p1w,
                                               const float* __restrict__ p2w,
                                               const float* __restrict__ p3w,
                                               u16* __restrict__ dst) {
  int i = blockIdx.x * 256 + threadIdx.x;  // 542208 total
  if (i < 294912) dst[i] = f2bf(piw[i]);
  else if (i < 442368) dst[i] = f2bf(pow_[i - 294912]);
  else if (i < 443904) { int j = i - 442368, o = j >> 5, k = j & 31;
    dst[i] = (k < 24) ? f2bf(p0w[o * 24 + k]) : (u16)0; }
  else if (i < 450048) { int j = i - 443904, o = j >> 6, k = j & 63;
    dst[i] = (k < 48) ? f2bf(p1w[o * 48 + k]) : (u16)0; }
  else if (i < 468480) dst[i] = f2bf(p2w[i - 450048]);
  else dst[i] = f2bf(p3w[i - 468480]);
}

__global__ __launch_bounds__(256) void k_cvtwL(const float* __restrict__ fc1,
                                               const float* __restrict__ fc2,
                                               u16* __restrict__ dst) {
  int i = blockIdx.x * 256 + threadIdx.x;  // 1179648 total
  if (i < 589824) dst[i] = f2bf(fc1[i]);
  else dst[i] = f2bf(fc2[i - 589824]);
}

// ---------------- NCHW -> NHWC transpose + LN1 apply ----------------
__global__ __launch_bounds__(256) void k_trln1(const float* __restrict__ x,
                                               const float* __restrict__ lnw,
                                               const float* __restrict__ lnb,
                                               const float* __restrict__ stats,
                                               u16* __restrict__ xn,
                                               u16* __restrict__ hn) {
  int pt = blockIdx.x, ct = blockIdx.y, b = blockIdx.z;
  __shared__ float xs[32][33], hs[32][33];
  float m = stats[b], rs = stats[32 + b];
  int t = threadIdx.x;
  int ci0 = t >> 5, pi = t & 31;
#pragma unroll
  for (int it = 0; it < 4; it++) {
    int ci = ci0 + it * 8;
    int c = ct * 32 + ci;
    size_t src = ((size_t)b * CDIM + c) * HW + pt * 32 + pi;
    size_t wsrc = (size_t)c * HW + pt * 32 + pi;
    float xv = x[src];
    xs[ci][pi] = xv;
    hs[ci][pi] = (xv - m) * rs * lnw[wsrc] + lnb[wsrc];
  }
  __syncthreads();
  int co = t & 31, pr0 = t >> 5;
#pragma unroll
  for (int it = 0; it < 4; it++) {
    int pr = pr0 + it * 8;
    int p = pt * 32 + pr;
    int c = ct * 32 + co;
    size_t dst = ((size_t)b * HW + p) * CDIM + c;
    xn[dst] = f2bf(xs[co][pr]);
    hn[dst] = f2bf(hs[co][pr]);
  }
}

// ---------------- m97-style 128x128 MFMA GEMM (BK=32, proven) ----------------
template <int MODE>
__global__ __launch_bounds__(256)
void k_mfma(const u16* __restrict__ A, const u16* __restrict__ Wb,
            const float* __restrict__ bias, void* __restrict__ Out,
            const u16* __restrict__ gate, int gate_off,
            const u16* __restrict__ resbf, const float* __restrict__ gvec,
            int m_base, int K, int O, int OS) {
  __shared__ u16 As[4096];
  __shared__ u16 Bs[4096];
  const int t = threadIdx.x;
  const int m0 = blockIdx.x * 128, o0 = blockIdx.y * 128;
  const int w = t >> 6, l = t & 63;
  const int wm = (w >> 1) * 64, wn = (w & 1) * 64;
  const int lr = l & 15, lk = (l >> 4) * 8;

  const u16* gA = A + (size_t)(m0 + w * 32 + (l >> 2)) * K + (l & 3) * 8;
  const u16* gB = Wb + (size_t)(o0 + w * 32 + (l >> 2)) * K + (l & 3) * 8;
  u16* ldsA0 = As + w * 1024;
  u16* ldsB0 = Bs + w * 1024;

  f4v acc[4][4];
#pragma unroll
  for (int i = 0; i < 4; i++)
#pragma unroll
    for (int j = 0; j < 4; j++) acc[i][j] = {};

  for (int k0 = 0; k0 < K; k0 += 32) {
    gload16(gA + k0, ldsA0);
    gload16(gA + 16 * K + k0, ldsA0 + 512);
    gload16(gB + k0, ldsB0);
    gload16(gB + 16 * K + k0, ldsB0 + 512);
    __syncthreads();
    s8v a[4], b[4];
#pragma unroll
    for (int mi = 0; mi < 4; mi++)
      a[mi] = *(const s8v*)&As[(wm + mi * 16 + lr) * 32 + lk];
#pragma unroll
    for (int fj = 0; fj < 4; fj++)
      b[fj] = *(const s8v*)&Bs[(wn + fj * 16 + lr) * 32 + lk];
#pragma unroll
    for (int mi = 0; mi < 4; mi++)
#pragma unroll
      for (int fj = 0; fj < 4; fj++)
        acc[mi][fj] = __builtin_amdgcn_mfma_f32_16x16x32_bf16(a[mi], b[fj], acc[mi][fj], 0, 0, 0);
    __syncthreads();
  }

  const int orow = (l >> 4) * 4;
#pragma unroll
  for (int mi = 0; mi < 4; mi++) {
    int p = m0 + wm + mi * 16 + orow;
#pragma unroll
    for (int fj = 0; fj < 4; fj++) {
      int o = o0 + wn + fj * 16 + lr;
      if (MODE == 1 && o >= OS) continue;
      float bo = (MODE == 1 && o >= O) ? 0.f : bias[o];
      float gv = (MODE == 2 || MODE == 4) ? gvec[o] : 0.f;
      if (MODE == 4) {
        int gp = m_base + p;
        float4 st;
        float* stp = &st.x;
#pragma unroll
        for (int r = 0; r < 4; r++)
          stp[r] = bf2f(resbf[(size_t)(gp + r) * CDIM + o]) + gv * (acc[mi][fj][r] + bo);
        int bb = gp >> 10, hw = gp & 1023;
        *(float4*)((float*)Out + ((size_t)bb * CDIM + o) * HW + hw) = st;
      } else {
#pragma unroll
        for (int r = 0; r < 4; r++) {
          float val = acc[mi][fj][r] + bo;
          size_t rowi = (size_t)(p + r);
          if (MODE == 0) {
            ((u16*)Out)[rowi * OS + o] = f2bf(val);
          } else if (MODE == 1) {
            float g = (o < O) ? bf2f(gate[rowi * 744 + gate_off + o]) : 0.f;
            ((u16*)Out)[rowi * OS + o] = (o < O) ? f2bf(val * g) : (u16)0;
          } else if (MODE == 2) {
            size_t idx = rowi * CDIM + o;
            ((u16*)Out)[idx] = f2bf(bf2f(resbf[idx]) + gv * val);
          } else if (MODE == 3) {
            ((u16*)Out)[rowi * OS + o] = f2bf(gelu_exact(val));
          }
        }
      }
    }
  }
}

// ---------------- 128x64-tile MFMA GEMM for small-N (BK=32, 12KB LDS) ----------
template <int MODE>
__global__ __launch_bounds__(256)
void k_mfma64(const u16* __restrict__ A, const u16* __restrict__ Wb,
              const float* __restrict__ bias, void* __restrict__ Out,
              const u16* __restrict__ gate, int gate_off,
              const u16* __restrict__ resbf, const float* __restrict__ gvec,
              int m_base, int K, int O, int OS) {
  __shared__ u16 As[4096];   // 128 rows x 32 k
  __shared__ u16 Bs[2048];   // 64 rows x 32 k
  const int t = threadIdx.x;
  const int m0 = blockIdx.x * 128, o0 = blockIdx.y * 64;
  const int w = t >> 6, l = t & 63;
  const int wm = w * 32;
  const int lr = l & 15, lk = (l >> 4) * 8;

  const u16* gA = A + (size_t)(m0 + w * 32 + (l >> 2)) * K + (l & 3) * 8;
  const u16* gB = Wb + (size_t)(o0 + w * 16 + (l >> 2)) * K + (l & 3) * 8;
  u16* ldsA0 = As + w * 1024;
  u16* ldsB0 = Bs + w * 512;

  f4v acc[2][4];
#pragma unroll
  for (int i = 0; i < 2; i++)
#pragma unroll
    for (int j = 0; j < 4; j++) acc[i][j] = {};

  for (int k0 = 0; k0 < K; k0 += 32) {
    gload16(gA + k0, ldsA0);
    gload16(gA + 16 * K + k0, ldsA0 + 512);
    gload16(gB + k0, ldsB0);
    __syncthreads();
    s8v a[2], b[4];
#pragma unroll
    for (int mi = 0; mi < 2; mi++)
      a[mi] = *(const s8v*)&As[(wm + mi * 16 + lr) * 32 + lk];
#pragma unroll
    for (int fj = 0; fj < 4; fj++)
      b[fj] = *(const s8v*)&Bs[(fj * 16 + lr) * 32 + lk];
#pragma unroll
    for (int mi = 0; mi < 2; mi++)
#pragma unroll
      for (int fj = 0; fj < 4; fj++)
        acc[mi][fj] = __builtin_amdgcn_mfma_f32_16x16x32_bf16(a[mi], b[fj], acc[mi][fj], 0, 0, 0);
    __syncthreads();
  }

  const int orow = (l >> 4) * 4;
#pragma unroll
  for (int mi = 0; mi < 2; mi++) {
    int p = m0 + wm + mi * 16 + orow;
#pragma unroll
    for (int fj = 0; fj < 4; fj++) {
      int o = o0 + fj * 16 + lr;
      if (MODE == 1 && o >= OS) continue;
      float bo = (MODE == 1 && o >= O) ? 0.f : bias[o];
      float gv = (MODE == 2 || MODE == 4) ? gvec[o] : 0.f;
      if (MODE == 4) {
        int gp = m_base + p;
        float4 st;
        float* stp = &st.x;
#pragma unroll
        for (int r = 0; r < 4; r++)
          stp[r] = bf2f(resbf[(size_t)(gp + r) * CDIM + o]) + gv * (acc[mi][fj][r] + bo);
        int bb = gp >> 10, hw = gp & 1023;
        *(float4*)((float*)Out + ((size_t)bb * CDIM + o) * HW + hw) = st;
      } else {
#pragma unroll
        for (int r = 0; r < 4; r++) {
          float val = acc[mi][fj][r] + bo;
          size_t rowi = (size_t)(p + r);
          if (MODE == 0) {
            ((u16*)Out)[rowi * OS + o] = f2bf(val);
          } else if (MODE == 1) {
            float g = (o < O) ? bf2f(gate[rowi * 744 + gate_off + o]) : 0.f;
            ((u16*)Out)[rowi * OS + o] = (o < O) ? f2bf(val * g) : (u16)0;
          } else if (MODE == 2) {
            size_t idx = rowi * CDIM + o;
            ((u16*)Out)[idx] = f2bf(bf2f(resbf[idx]) + gv * val);
          } else if (MODE == 3) {
            ((u16*)Out)[rowi * OS + o] = f2bf(gelu_exact(val));
          }
        }
      }
    }
  }
}

// ---------------- depthwise 7x7, NHWC, fp16 pk_fma, 2 channels/thread ----------
// block 256 = 32 chpair x 4 dy x 2 xh (xh wave-uniform). Each thread: 2ch x 16x.
__global__ __launch_bounds__(256) void k_dwconv(const u16* __restrict__ fused,
                                                const float* __restrict__ w,
                                                const float* __restrict__ bias,
                                                u16* __restrict__ dwo) {
  const int ys = blockIdx.x;   // 8 strips of 4 rows
  const int cb = blockIdx.y;   // 12 channel slabs of 64
  const int b = blockIdx.z;
  __shared__ _Float16 tile[10][32][64];
  __shared__ h2v wk2[32][49];
  const int c0 = cb * 64;
  const int t = threadIdx.x;
  // stage packed fp16 weight pairs
  for (int i = t; i < 32 * 49; i += 256) {
    int cc = i / 49, k = i - cc * 49;
    int ch = c0 + cc * 2;
    h2v wv = {};
    if (ch < 744) {
      wv[0] = (_Float16)w[(size_t)ch * 49 + k];
      wv[1] = (_Float16)w[(size_t)(ch + 1) * 49 + k];
    }
    wk2[cc][k] = wv;
  }
  // stage tile (bf16 global -> fp16 LDS)
  {
    const int lx = t >> 3, lco = (t & 7) * 8;
    const int fch = 24 + c0 + lco;
#pragma unroll
    for (int yy = 0; yy < 10; yy++) {
      int y = ys * 4 - 3 + yy;
      h8v v = {};
      if (y >= 0 && y < 32 && fch < 768) {
        U8 u;
        u.v = *(const s8v*)(fused + ((size_t)b * HW + y * 32 + lx) * 768 + fch);
#pragma unroll
        for (int i = 0; i < 8; i++) v[i] = (_Float16)bf2f(u.u[i]);
      }
      *(h8v*)&tile[yy][lx][lco] = v;
    }
  }
  __syncthreads();
  const int c2 = t & 31;
  const int dy = (t >> 5) & 3;
  const int xh = t >> 7;          // wave-uniform (waves 0,1 -> 0; waves 2,3 -> 1)
  const int ch0 = c0 + c2 * 2;
  const bool valid = ch0 < 744;
  h2v acc[16];
#pragma unroll
  for (int x = 0; x < 16; x++) acc[x] = (h2v){};
#pragma unroll
  for (int ky = 0; ky < 7; ky++) {
    const int yy = dy + ky;
    h2v win[22];
    if (xh == 0) {
      win[0] = (h2v){}; win[1] = (h2v){}; win[2] = (h2v){};
#pragma unroll
      for (int j = 3; j < 22; j++)
        win[j] = *(const h2v*)&tile[yy][j - 3][c2 * 2];
    } else {
#pragma unroll
      for (int j = 0; j < 19; j++)
        win[j] = *(const h2v*)&tile[yy][13 + j][c2 * 2];
      win[19] = (h2v){}; win[20] = (h2v){}; win[21] = (h2v){};
    }
#pragma unroll
    for (int kx = 0; kx < 7; kx++) {
      h2v wv = wk2[c2][ky * 7 + kx];
#pragma unroll
      for (int x = 0; x < 16; x++) acc[x] += win[x + kx] * wv;
    }
  }
  if (valid) {
    const float bv0 = bias[ch0], bv1 = bias[ch0 + 1];
    const int yout = ys * 4 + dy;
    const size_t prow = (size_t)b * HW + yout * 32 + xh * 16;
#pragma unroll
    for (int x = 0; x < 16; x++) {
      float v0 = ((float)acc[x][0] + bv0) * (1.f / 3.f);
      float v1 = ((float)acc[x][1] + bv1) * (1.f / 3.f);
      unsigned int pk = (unsigned int)f2bf(v0) | ((unsigned int)f2bf(v1) << 16);
      *(unsigned int*)&dwo[(prow + x) * 744 + ch0] = pk;
    }
  }
}

// ---------------- y0 = pwa * dw[:,:24], padded stride 32, vectorized ----------
__global__ __launch_bounds__(256) void k_y0(const u16* __restrict__ fused,
                                            const u16* __restrict__ dwo,
                                            u16* __restrict__ y0) {
  int i = blockIdx.x * 256 + threadIdx.x;  // MTOT*4 threads, 8 ch each
  int p = i >> 2, cq = (i & 3) * 8;
  U8 res;
  if (cq < 24) {
    U8 a, d;
    a.v = *(const s8v*)(fused + (size_t)p * 768 + cq);
    d.v = *(const s8v*)(dwo + (size_t)p * 744 + cq);
#pragma unroll
    for (int j = 0; j < 8; j++) res.u[j] = f2bf(bf2f(a.u[j]) * bf2f(d.u[j]));
  } else {
#pragma unroll
    for (int j = 0; j < 8; j++) res.u[j] = 0;
  }
  *(s8v*)(y0 + (size_t)p * 32 + cq) = res.v;
}

// ---------------- LN2 (row over 384 contiguous channels, bf16 in/out) ----------------
__global__ __launch_bounds__(256) void k_ln2(const u16* __restrict__ xm,
                                             const float* __restrict__ w,
                                             const float* __restrict__ bb,
                                             u16* __restrict__ outp) {
  int row = blockIdx.x * 4 + (threadIdx.x >> 6);
  int l = threadIdx.x & 63;
  float v[8];
  float s = 0.f, s2 = 0.f;
  if (l < 48) {
    U8 u;
    u.v = *(const s8v*)(xm + (size_t)row * CDIM + l * 8);
#pragma unroll
    for (int i = 0; i < 8; i++) {
      v[i] = bf2f(u.u[i]);
      s += v[i]; s2 += v[i] * v[i];
    }
  }
#pragma unroll
  for (int off = 32; off > 0; off >>= 1) {
    s += __shfl_xor(s, off);
    s2 += __shfl_xor(s2, off);
  }
  const float inv_n = 1.f / CDIM;
  float m = s * inv_n;
  float rs = rsqrtf(s2 * inv_n - m * m + EPS);
  if (l < 48) {
    U8 res;
#pragma unroll
    for (int i = 0; i < 8; i++) {
      int c = l * 8 + i;
      res.u[i] = f2bf((v[i] - m) * rs * w[c] + bb[c]);
    }
    *(s8v*)(outp + (size_t)row * CDIM + l * 8) = res.v;
  }
}

extern "C" void kernel_launch(void* const* d_in, const int* in_sizes, int n_in,
                              void* d_out, int out_size, void* d_ws, size_t ws_size,
                              hipStream_t stream) {
  const float* x          = (const float*)d_in[0];
  const float* ln1_w      = (const float*)d_in[1];
  const float* ln1_b      = (const float*)d_in[2];
  const float* proj_in_w  = (const float*)d_in[3];
  const float* proj_in_b  = (const float*)d_in[4];
  const float* dw_w       = (const float*)d_in[5];
  const float* dw_b       = (const float*)d_in[6];
  const float* pw0_w      = (const float*)d_in[7];
  const float* pw0_b      = (const float*)d_in[8];
  const float* pw1_w      = (const float*)d_in[9];
  const float* pw1_b      = (const float*)d_in[10];
  const float* pw2_w      = (const float*)d_in[11];
  const float* pw2_b      = (const float*)d_in[12];
  const float* pw3_w      = (const float*)d_in[13];
  const float* pw3_b      = (const float*)d_in[14];
  const float* proj_out_w = (const float*)d_in[15];
  const float* proj_out_b = (const float*)d_in[16];
  const float* ln2_w      = (const float*)d_in[17];
  const float* ln2_b      = (const float*)d_in[18];
  const float* fc1_w      = (const float*)d_in[19];
  const float* fc1_b      = (const float*)d_in[20];
  const float* fc2_w      = (const float*)d_in[21];
  const float* fc2_b      = (const float*)d_in[22];
  const float* gamma1     = (const float*)d_in[23];
  const float* gamma2     = (const float*)d_in[24];
  float* out = (float*)d_out;

  const size_t MiB = 1ull << 20;
  char* ws = (char*)d_ws;
  u16* xn   = (u16*)(ws + 0);            // [0,24) x bf16 NHWC; dead after proj_out
  u16* hn   = (u16*)(ws + 24 * MiB);     // [24,48); dead after proj_in
  u16* fus  = (u16*)(ws + 48 * MiB);     // [48,96); dead after k_y0
  u16* dw   = (u16*)(ws + 96 * MiB);     // [96,142.5); dead after pw3
  u16* wE   = (u16*)(ws + 142 * MiB + 512 * 1024);  // early bf16 weights, 1.04 MiB
  float* stats = (float*)(ws + 143 * MiB + 768 * 1024);
  float* part  = stats + 64;
  u16* y0 = (u16*)(ws + 24 * MiB);       // [24,26) stride 32 (hn dead)
  u16* y1 = (u16*)(ws + 26 * MiB);       // [26,30) stride 64
  u16* y2 = (u16*)(ws + 30 * MiB);       // [30,36) stride 96
  u16* y3 = (u16*)(ws + 36 * MiB);       // [36,48) stride 192
  u16* y4 = (u16*)(ws + 48 * MiB);       // [48,72) stride 384 (fus dead)
  u16* xmid = (u16*)(ws + 72 * MiB);     // [72,96) bf16 NHWC
  u16* ln2h = (u16*)(ws + 0);            // [0,24) (xn dead after proj_out)
  u16* fc1b = (u16*)(ws + 24 * MiB);     // late weights (y* dead)
  u16* fc2b = fc1b + 589824;
  u16* h1 = (u16*)(ws + 96 * MiB);       // [96,144) 16-batch chunk

  u16* piw_b = wE;
  u16* pow_b = wE + 294912;
  u16* pw0b  = wE + 442368;
  u16* pw1b  = wE + 443904;
  u16* pw2b  = wE + 450048;
  u16* pw3b  = wE + 468480;

  k_statsA<<<1024, 256, 0, stream>>>(x, part);
  k_statsB<<<1, 64, 0, stream>>>(part, stats);
  k_cvtwE<<<2118, 256, 0, stream>>>(proj_in_w, proj_out_w, pw0_w, pw1_w, pw2_w, pw3_w, wE);
  k_trln1<<<dim3(32, 12, NB), 256, 0, stream>>>(x, ln1_w, ln1_b, stats, xn, hn);
  // proj_in: M=32768, K=384, O=768 (128x128 tile)
  k_mfma<0><<<dim3(256, 6), 256, 0, stream>>>(hn, piw_b, proj_in_b, fus, nullptr, 0,
                                              nullptr, nullptr, 0, 384, 768, 768);
  // depthwise 7x7 (fp16 pk_fma), then y0
  k_dwconv<<<dim3(8, 12, NB), 256, 0, stream>>>(fus, dw_w, dw_b, dw);
  k_y0<<<(MTOT * 4) / 256, 256, 0, stream>>>(fus, dw, y0);
  // pw chain (128x64 tiles for small N)
  k_mfma64<1><<<dim3(256, 1), 256, 0, stream>>>(y0, pw0b, pw0_b, y1, dw, 24, nullptr,
                                                nullptr, 0, 32, 48, 64);
  k_mfma64<1><<<dim3(256, 2), 256, 0, stream>>>(y1, pw1b, pw1_b, y2, dw, 72, nullptr,
                                                nullptr, 0, 64, 96, 96);
  k_mfma64<1><<<dim3(256, 3), 256, 0, stream>>>(y2, pw2b, pw2_b, y3, dw, 168, nullptr,
                                                nullptr, 0, 96, 192, 192);
  k_mfma64<1><<<dim3(256, 6), 256, 0, stream>>>(y3, pw3b, pw3_b, y4, dw, 360, nullptr,
                                                nullptr, 0, 192, 384, 384);
  // proj_out + gamma1 residual -> xmid (bf16), 128x64 tile
  k_mfma64<2><<<dim3(256, 6), 256, 0, stream>>>(y4, pow_b, proj_out_b, xmid, nullptr, 0,
                                                xn, gamma1, 0, 384, 384, 384);
  k_ln2<<<MTOT / 4, 256, 0, stream>>>(xmid, ln2_w, ln2_b, ln2h);
  k_cvtwL<<<4608, 256, 0, stream>>>(fc1_w, fc2_w, fc1b);
  // MLP in 2 chunks of 16 batches
  for (int ch = 0; ch < 2; ch++) {
    int m_base = ch * 16384;
    k_mfma<3><<<dim3(128, 12), 256, 0, stream>>>(ln2h + (size_t)m_base * CDIM, fc1b,
                                                 fc1_b, h1, nullptr, 0, nullptr, nullptr,
                                                 0, 384, 1536, 1536);
    k_mfma64<4><<<dim3(128, 6), 256, 0, stream>>>(h1, fc2b, fc2_b, out, nullptr, 0, xmid,
                                                  gamma2, m_base, 1536, 384, 384);
  }
}

// Round 11
// 377.065 us; speedup vs baseline: 1.0432x; 1.0432x over previous
//
#include <hip/hip_runtime.h>
#include <math.h>

#define HW 1024
#define CDIM 384
#define NB 32
#define MTOT (NB * HW)
#define EPS 1e-5f

typedef unsigned short u16;
typedef short s8v __attribute__((ext_vector_type(8)));
typedef float f4v __attribute__((ext_vector_type(4)));

union U8 { s8v v; u16 u[8]; };

__device__ __forceinline__ float bf2f(u16 u) {
  union { float f; unsigned int i; } x; x.i = ((unsigned int)u) << 16; return x.f;
}
__device__ __forceinline__ u16 f2bf(float f) {
  union { float f; unsigned int i; } x; x.f = f;
  unsigned int r = (x.i + 0x7FFFu + ((x.i >> 16) & 1u)) >> 16;
  return (u16)r;
}
__device__ __forceinline__ float gelu_exact(float v) {
  return 0.5f * v * (1.f + erff(v * 0.70710678118654752f));
}

// async global->LDS, 16B per lane; LDS dest = wave-uniform base + lane*16
__device__ __forceinline__ void gload16(const u16* g, u16* l) {
  __builtin_amdgcn_global_load_lds(
      (const __attribute__((address_space(1))) unsigned int*)(unsigned long long)(const void*)g,
      (__attribute__((address_space(3))) unsigned int*)(unsigned int)(unsigned long long)(void*)l,
      16, 0, 0);
}

// ---------------- LN1 stats, two-stage ----------------
__global__ __launch_bounds__(256) void k_statsA(const float* __restrict__ x,
                                                float* __restrict__ part) {
  int blk = blockIdx.x;
  const float4* xb = (const float4*)(x + (size_t)blk * 12288);
  float s = 0.f, s2 = 0.f;
  for (int i = threadIdx.x; i < 3072; i += 256) {
    float4 v = xb[i];
    s += v.x + v.y + v.z + v.w;
    s2 += v.x * v.x + v.y * v.y + v.z * v.z + v.w * v.w;
  }
  __shared__ float ls[256], ls2[256];
  ls[threadIdx.x] = s; ls2[threadIdx.x] = s2;
  __syncthreads();
  for (int off = 128; off > 0; off >>= 1) {
    if (threadIdx.x < off) {
      ls[threadIdx.x] += ls[threadIdx.x + off];
      ls2[threadIdx.x] += ls2[threadIdx.x + off];
    }
    __syncthreads();
  }
  if (threadIdx.x == 0) { part[blk * 2] = ls[0]; part[blk * 2 + 1] = ls2[0]; }
}

__global__ void k_statsB(const float* __restrict__ part, float* __restrict__ stats) {
  int b = threadIdx.x;
  if (b >= 32) return;
  float s = 0.f, s2 = 0.f;
  for (int i = 0; i < 32; i++) {
    s += part[(b * 32 + i) * 2];
    s2 += part[(b * 32 + i) * 2 + 1];
  }
  const float inv_n = 1.f / (CDIM * HW);
  float m = s * inv_n;
  stats[b] = m;
  stats[32 + b] = rsqrtf(s2 * inv_n - m * m + EPS);
}

// ---------------- weight f32->bf16 conversion ----------------
__global__ __launch_bounds__(256) void k_cvtwE(const float* __restrict__ piw,
                                               const float* __restrict__ pow_,
                                               const float* __restrict__ p0w,
                                               const float* __restrict__ p1w,
                                               const float* __restrict__ p2w,
                                               const float* __restrict__ p3w,
                                               u16* __restrict__ dst) {
  int i = blockIdx.x * 256 + threadIdx.x;  // 542208 total
  if (i < 294912) dst[i] = f2bf(piw[i]);
  else if (i < 442368) dst[i] = f2bf(pow_[i - 294912]);
  else if (i < 443904) { int j = i - 442368, o = j >> 5, k = j & 31;
    dst[i] = (k < 24) ? f2bf(p0w[o * 24 + k]) : (u16)0; }
  else if (i < 450048) { int j = i - 443904, o = j >> 6, k = j & 63;
    dst[i] = (k < 48) ? f2bf(p1w[o * 48 + k]) : (u16)0; }
  else if (i < 468480) dst[i] = f2bf(p2w[i - 450048]);
  else dst[i] = f2bf(p3w[i - 468480]);
}

__global__ __launch_bounds__(256) void k_cvtwL(const float* __restrict__ fc1,
                                               const float* __restrict__ fc2,
                                               u16* __restrict__ dst) {
  int i = blockIdx.x * 256 + threadIdx.x;  // 1179648 total
  if (i < 589824) dst[i] = f2bf(fc1[i]);
  else dst[i] = f2bf(fc2[i - 589824]);
}

// ---------------- NCHW -> NHWC transpose + LN1 apply ----------------
__global__ __launch_bounds__(256) void k_trln1(const float* __restrict__ x,
                                               const float* __restrict__ lnw,
                                               const float* __restrict__ lnb,
                                               const float* __restrict__ stats,
                                               u16* __restrict__ xn,
                                               u16* __restrict__ hn) {
  int pt = blockIdx.x, ct = blockIdx.y, b = blockIdx.z;
  __shared__ float xs[32][33], hs[32][33];
  float m = stats[b], rs = stats[32 + b];
  int t = threadIdx.x;
  int ci0 = t >> 5, pi = t & 31;
#pragma unroll
  for (int it = 0; it < 4; it++) {
    int ci = ci0 + it * 8;
    int c = ct * 32 + ci;
    size_t src = ((size_t)b * CDIM + c) * HW + pt * 32 + pi;
    size_t wsrc = (size_t)c * HW + pt * 32 + pi;
    float xv = x[src];
    xs[ci][pi] = xv;
    hs[ci][pi] = (xv - m) * rs * lnw[wsrc] + lnb[wsrc];
  }
  __syncthreads();
  int co = t & 31, pr0 = t >> 5;
#pragma unroll
  for (int it = 0; it < 4; it++) {
    int pr = pr0 + it * 8;
    int p = pt * 32 + pr;
    int c = ct * 32 + co;
    size_t dst = ((size_t)b * HW + p) * CDIM + c;
    xn[dst] = f2bf(xs[co][pr]);
    hn[dst] = f2bf(hs[co][pr]);
  }
}

// ---------------- 128x128 MFMA GEMM, BK=32, double-buffered prefetch ----------
template <int MODE>
__global__ __launch_bounds__(256)
void k_mfma(const u16* __restrict__ A, const u16* __restrict__ Wb,
            const float* __restrict__ bias, void* __restrict__ Out,
            const u16* __restrict__ gate, int gate_off,
            const u16* __restrict__ resbf, const float* __restrict__ gvec,
            int m_base, int K, int O, int OS) {
  __shared__ u16 As[8192];   // 2 buffers x 128 rows x 32 k
  __shared__ u16 Bs[8192];
  const int t = threadIdx.x;
  const int m0 = blockIdx.x * 128, o0 = blockIdx.y * 128;
  const int w = t >> 6, l = t & 63;
  const int wm = (w >> 1) * 64, wn = (w & 1) * 64;
  const int lr = l & 15, lk = (l >> 4) * 8;

  const u16* gA = A + (size_t)(m0 + w * 32 + (l >> 2)) * K + (l & 3) * 8;
  const u16* gB = Wb + (size_t)(o0 + w * 32 + (l >> 2)) * K + (l & 3) * 8;
  u16* ldsA0 = As + w * 1024;
  u16* ldsB0 = Bs + w * 1024;

  f4v acc[4][4];
#pragma unroll
  for (int i = 0; i < 4; i++)
#pragma unroll
    for (int j = 0; j < 4; j++) acc[i][j] = {};

  // prologue: stage k=0 into buffer 0
  gload16(gA, ldsA0);
  gload16(gA + 16 * K, ldsA0 + 512);
  gload16(gB, ldsB0);
  gload16(gB + 16 * K, ldsB0 + 512);
  __syncthreads();

  int cur = 0;
  for (int k0 = 0; k0 < K; k0 += 32) {
    // prefetch next tile into the other buffer (overlaps MFMA below)
    if (k0 + 32 < K) {
      const int nx = (cur ^ 1) * 4096;
      gload16(gA + k0 + 32, ldsA0 + nx);
      gload16(gA + 16 * K + k0 + 32, ldsA0 + nx + 512);
      gload16(gB + k0 + 32, ldsB0 + nx);
      gload16(gB + 16 * K + k0 + 32, ldsB0 + nx + 512);
    }
    const int cb = cur * 4096;
    s8v a[4], b[4];
#pragma unroll
    for (int mi = 0; mi < 4; mi++)
      a[mi] = *(const s8v*)&As[cb + (wm + mi * 16 + lr) * 32 + lk];
#pragma unroll
    for (int fj = 0; fj < 4; fj++)
      b[fj] = *(const s8v*)&Bs[cb + (wn + fj * 16 + lr) * 32 + lk];
#pragma unroll
    for (int mi = 0; mi < 4; mi++)
#pragma unroll
      for (int fj = 0; fj < 4; fj++)
        acc[mi][fj] = __builtin_amdgcn_mfma_f32_16x16x32_bf16(a[mi], b[fj], acc[mi][fj], 0, 0, 0);
    __syncthreads();  // drains prefetch; all waves done reading cur
    cur ^= 1;
  }

  const int orow = (l >> 4) * 4;
#pragma unroll
  for (int mi = 0; mi < 4; mi++) {
    int p = m0 + wm + mi * 16 + orow;
#pragma unroll
    for (int fj = 0; fj < 4; fj++) {
      int o = o0 + wn + fj * 16 + lr;
      if (MODE == 1 && o >= OS) continue;
      float bo = (MODE == 1 && o >= O) ? 0.f : bias[o];
      float gv = (MODE == 2 || MODE == 4) ? gvec[o] : 0.f;
      if (MODE == 4) {
        int gp = m_base + p;
        float4 st;
        float* stp = &st.x;
#pragma unroll
        for (int r = 0; r < 4; r++)
          stp[r] = bf2f(resbf[(size_t)(gp + r) * CDIM + o]) + gv * (acc[mi][fj][r] + bo);
        int bb = gp >> 10, hw = gp & 1023;
        *(float4*)((float*)Out + ((size_t)bb * CDIM + o) * HW + hw) = st;
      } else {
#pragma unroll
        for (int r = 0; r < 4; r++) {
          float val = acc[mi][fj][r] + bo;
          size_t rowi = (size_t)(p + r);
          if (MODE == 0) {
            ((u16*)Out)[rowi * OS + o] = f2bf(val);
          } else if (MODE == 1) {
            float g = (o < O) ? bf2f(gate[rowi * 744 + gate_off + o]) : 0.f;
            ((u16*)Out)[rowi * OS + o] = (o < O) ? f2bf(val * g) : (u16)0;
          } else if (MODE == 2) {
            size_t idx = rowi * CDIM + o;
            ((u16*)Out)[idx] = f2bf(bf2f(resbf[idx]) + gv * val);
          } else if (MODE == 3) {
            ((u16*)Out)[rowi * OS + o] = f2bf(gelu_exact(val));
          }
        }
      }
    }
  }
}

// ---------------- 128x64-tile MFMA GEMM, small-N, double-buffered ----------
template <int MODE>
__global__ __launch_bounds__(256)
void k_mfma64(const u16* __restrict__ A, const u16* __restrict__ Wb,
              const float* __restrict__ bias, void* __restrict__ Out,
              const u16* __restrict__ gate, int gate_off,
              const u16* __restrict__ resbf, const float* __restrict__ gvec,
              int m_base, int K, int O, int OS) {
  __shared__ u16 As[8192];   // 2 x 128 x 32
  __shared__ u16 Bs[4096];   // 2 x 64 x 32
  const int t = threadIdx.x;
  const int m0 = blockIdx.x * 128, o0 = blockIdx.y * 64;
  const int w = t >> 6, l = t & 63;
  const int wm = w * 32;
  const int lr = l & 15, lk = (l >> 4) * 8;

  const u16* gA = A + (size_t)(m0 + w * 32 + (l >> 2)) * K + (l & 3) * 8;
  const u16* gB = Wb + (size_t)(o0 + w * 16 + (l >> 2)) * K + (l & 3) * 8;
  u16* ldsA0 = As + w * 1024;
  u16* ldsB0 = Bs + w * 512;

  f4v acc[2][4];
#pragma unroll
  for (int i = 0; i < 2; i++)
#pragma unroll
    for (int j = 0; j < 4; j++) acc[i][j] = {};

  gload16(gA, ldsA0);
  gload16(gA + 16 * K, ldsA0 + 512);
  gload16(gB, ldsB0);
  __syncthreads();

  int cur = 0;
  for (int k0 = 0; k0 < K; k0 += 32) {
    if (k0 + 32 < K) {
      gload16(gA + k0 + 32, ldsA0 + (cur ^ 1) * 4096);
      gload16(gA + 16 * K + k0 + 32, ldsA0 + (cur ^ 1) * 4096 + 512);
      gload16(gB + k0 + 32, ldsB0 + (cur ^ 1) * 2048);
    }
    const int cbA = cur * 4096, cbB = cur * 2048;
    s8v a[2], b[4];
#pragma unroll
    for (int mi = 0; mi < 2; mi++)
      a[mi] = *(const s8v*)&As[cbA + (wm + mi * 16 + lr) * 32 + lk];
#pragma unroll
    for (int fj = 0; fj < 4; fj++)
      b[fj] = *(const s8v*)&Bs[cbB + (fj * 16 + lr) * 32 + lk];
#pragma unroll
    for (int mi = 0; mi < 2; mi++)
#pragma unroll
      for (int fj = 0; fj < 4; fj++)
        acc[mi][fj] = __builtin_amdgcn_mfma_f32_16x16x32_bf16(a[mi], b[fj], acc[mi][fj], 0, 0, 0);
    __syncthreads();
    cur ^= 1;
  }

  const int orow = (l >> 4) * 4;
#pragma unroll
  for (int mi = 0; mi < 2; mi++) {
    int p = m0 + wm + mi * 16 + orow;
#pragma unroll
    for (int fj = 0; fj < 4; fj++) {
      int o = o0 + fj * 16 + lr;
      if (MODE == 1 && o >= OS) continue;
      float bo = (MODE == 1 && o >= O) ? 0.f : bias[o];
      float gv = (MODE == 2 || MODE == 4) ? gvec[o] : 0.f;
      if (MODE == 4) {
        int gp = m_base + p;
        float4 st;
        float* stp = &st.x;
#pragma unroll
        for (int r = 0; r < 4; r++)
          stp[r] = bf2f(resbf[(size_t)(gp + r) * CDIM + o]) + gv * (acc[mi][fj][r] + bo);
        int bb = gp >> 10, hw = gp & 1023;
        *(float4*)((float*)Out + ((size_t)bb * CDIM + o) * HW + hw) = st;
      } else {
#pragma unroll
        for (int r = 0; r < 4; r++) {
          float val = acc[mi][fj][r] + bo;
          size_t rowi = (size_t)(p + r);
          if (MODE == 0) {
            ((u16*)Out)[rowi * OS + o] = f2bf(val);
          } else if (MODE == 1) {
            float g = (o < O) ? bf2f(gate[rowi * 744 + gate_off + o]) : 0.f;
            ((u16*)Out)[rowi * OS + o] = (o < O) ? f2bf(val * g) : (u16)0;
          } else if (MODE == 2) {
            size_t idx = rowi * CDIM + o;
            ((u16*)Out)[idx] = f2bf(bf2f(resbf[idx]) + gv * val);
          } else if (MODE == 3) {
            ((u16*)Out)[rowi * OS + o] = f2bf(gelu_exact(val));
          }
        }
      }
    }
  }
}

// ---------------- depthwise 7x7, NHWC, 64-ch slabs x 4-row strips (R8 proven) ----
__global__ __launch_bounds__(256) void k_dwconv(const u16* __restrict__ fused,
                                                const float* __restrict__ w,
                                                const float* __restrict__ bias,
                                                u16* __restrict__ dwo) {
  const int ys = blockIdx.x;   // 8 strips of 4 rows
  const int cb = blockIdx.y;   // 12 channel slabs of 64
  const int b = blockIdx.z;
  __shared__ u16 tile[10][32][64];
  __shared__ float wk[64][49];
  const int c0 = cb * 64;
  const int t = threadIdx.x;
  for (int i = t; i < 64 * 64; i += 256) {
    int k = i >> 6, cc = i & 63;
    if (k < 49) wk[cc][k] = (c0 + cc < 744) ? w[(size_t)(c0 + cc) * 49 + k] : 0.f;
  }
  const int lx = t >> 3, lco = (t & 7) * 8;
  const int fch = 24 + c0 + lco;
#pragma unroll
  for (int yy = 0; yy < 10; yy++) {
    int y = ys * 4 - 3 + yy;
    s8v v = {0, 0, 0, 0, 0, 0, 0, 0};
    if (y >= 0 && y < 32 && fch < 768)
      v = *(const s8v*)(fused + ((size_t)b * HW + y * 32 + lx) * 768 + fch);
    *(s8v*)&tile[yy][lx][lco] = v;
  }
  __syncthreads();
  const int c = t & 63, dy = t >> 6;
  const bool valid = (c0 + c) < 744;
  const float bv = valid ? bias[c0 + c] : 0.f;
  float acc[32];
#pragma unroll
  for (int x = 0; x < 32; x++) acc[x] = 0.f;
#pragma unroll
  for (int ky = 0; ky < 7; ky++) {
    int yy = dy + ky;
    float r[38];
    r[0] = r[1] = r[2] = 0.f; r[35] = r[36] = r[37] = 0.f;
#pragma unroll
    for (int x = 0; x < 32; x++) r[x + 3] = bf2f(tile[yy][x][c]);
#pragma unroll
    for (int kx = 0; kx < 7; kx++) {
      float wv = wk[c][ky * 7 + kx];
#pragma unroll
      for (int x = 0; x < 32; x++) acc[x] += r[x + kx] * wv;
    }
  }
  if (valid) {
    const int yout = ys * 4 + dy;
    const size_t prow = (size_t)b * HW + yout * 32;
#pragma unroll
    for (int x = 0; x < 32; x++)
      dwo[(prow + x) * 744 + c0 + c] = f2bf((acc[x] + bv) * (1.f / 3.f));
  }
}

// ---------------- y0 = pwa * dw[:,:24], padded stride 32 (R9 proven) ----------
__global__ __launch_bounds__(256) void k_y0(const u16* __restrict__ fused,
                                            const u16* __restrict__ dwo,
                                            u16* __restrict__ y0) {
  int i = blockIdx.x * 256 + threadIdx.x;  // MTOT*32
  int p = i >> 5, c = i & 31;
  y0[i] = (c < 24) ? f2bf(bf2f(fused[(size_t)p * 768 + c]) * bf2f(dwo[(size_t)p * 744 + c]))
                   : (u16)0;
}

// ---------------- LN2 (row over 384 contiguous channels, bf16 in/out) ----------------
__global__ __launch_bounds__(256) void k_ln2(const u16* __restrict__ xm,
                                             const float* __restrict__ w,
                                             const float* __restrict__ bb,
                                             u16* __restrict__ outp) {
  int row = blockIdx.x * 4 + (threadIdx.x >> 6);
  int l = threadIdx.x & 63;
  float v[8];
  float s = 0.f, s2 = 0.f;
  if (l < 48) {
    U8 u;
    u.v = *(const s8v*)(xm + (size_t)row * CDIM + l * 8);
#pragma unroll
    for (int i = 0; i < 8; i++) {
      v[i] = bf2f(u.u[i]);
      s += v[i]; s2 += v[i] * v[i];
    }
  }
#pragma unroll
  for (int off = 32; off > 0; off >>= 1) {
    s += __shfl_xor(s, off);
    s2 += __shfl_xor(s2, off);
  }
  const float inv_n = 1.f / CDIM;
  float m = s * inv_n;
  float rs = rsqrtf(s2 * inv_n - m * m + EPS);
  if (l < 48) {
    U8 res;
#pragma unroll
    for (int i = 0; i < 8; i++) {
      int c = l * 8 + i;
      res.u[i] = f2bf((v[i] - m) * rs * w[c] + bb[c]);
    }
    *(s8v*)(outp + (size_t)row * CDIM + l * 8) = res.v;
  }
}

extern "C" void kernel_launch(void* const* d_in, const int* in_sizes, int n_in,
                              void* d_out, int out_size, void* d_ws, size_t ws_size,
                              hipStream_t stream) {
  const float* x          = (const float*)d_in[0];
  const float* ln1_w      = (const float*)d_in[1];
  const float* ln1_b      = (const float*)d_in[2];
  const float* proj_in_w  = (const float*)d_in[3];
  const float* proj_in_b  = (const float*)d_in[4];
  const float* dw_w       = (const float*)d_in[5];
  const float* dw_b       = (const float*)d_in[6];
  const float* pw0_w      = (const float*)d_in[7];
  const float* pw0_b      = (const float*)d_in[8];
  const float* pw1_w      = (const float*)d_in[9];
  const float* pw1_b      = (const float*)d_in[10];
  const float* pw2_w      = (const float*)d_in[11];
  const float* pw2_b      = (const float*)d_in[12];
  const float* pw3_w      = (const float*)d_in[13];
  const float* pw3_b      = (const float*)d_in[14];
  const float* proj_out_w = (const float*)d_in[15];
  const float* proj_out_b = (const float*)d_in[16];
  const float* ln2_w      = (const float*)d_in[17];
  const float* ln2_b      = (const float*)d_in[18];
  const float* fc1_w      = (const float*)d_in[19];
  const float* fc1_b      = (const float*)d_in[20];
  const float* fc2_w      = (const float*)d_in[21];
  const float* fc2_b      = (const float*)d_in[22];
  const float* gamma1     = (const float*)d_in[23];
  const float* gamma2     = (const float*)d_in[24];
  float* out = (float*)d_out;

  const size_t MiB = 1ull << 20;
  char* ws = (char*)d_ws;
  u16* xn   = (u16*)(ws + 0);            // [0,24) x bf16 NHWC; dead after proj_out
  u16* hn   = (u16*)(ws + 24 * MiB);     // [24,48); dead after proj_in
  u16* fus  = (u16*)(ws + 48 * MiB);     // [48,96); dead after k_y0
  u16* dw   = (u16*)(ws + 96 * MiB);     // [96,142.5); dead after pw3
  u16* wE   = (u16*)(ws + 142 * MiB + 512 * 1024);  // early bf16 weights, 1.04 MiB
  float* stats = (float*)(ws + 143 * MiB + 768 * 1024);
  float* part  = stats + 64;
  u16* y0 = (u16*)(ws + 24 * MiB);       // [24,26) stride 32 (hn dead)
  u16* y1 = (u16*)(ws + 26 * MiB);       // [26,30) stride 64
  u16* y2 = (u16*)(ws + 30 * MiB);       // [30,36) stride 96
  u16* y3 = (u16*)(ws + 36 * MiB);       // [36,48) stride 192
  u16* y4 = (u16*)(ws + 48 * MiB);       // [48,72) stride 384 (fus dead)
  u16* xmid = (u16*)(ws + 72 * MiB);     // [72,96) bf16 NHWC
  u16* ln2h = (u16*)(ws + 0);            // [0,24) (xn dead after proj_out)
  u16* fc1b = (u16*)(ws + 24 * MiB);     // late weights (y* dead)
  u16* fc2b = fc1b + 589824;
  u16* h1 = (u16*)(ws + 96 * MiB);       // [96,144) 16-batch chunk

  u16* piw_b = wE;
  u16* pow_b = wE + 294912;
  u16* pw0b  = wE + 442368;
  u16* pw1b  = wE + 443904;
  u16* pw2b  = wE + 450048;
  u16* pw3b  = wE + 468480;

  k_statsA<<<1024, 256, 0, stream>>>(x, part);
  k_statsB<<<1, 64, 0, stream>>>(part, stats);
  k_cvtwE<<<2118, 256, 0, stream>>>(proj_in_w, proj_out_w, pw0_w, pw1_w, pw2_w, pw3_w, wE);
  k_trln1<<<dim3(32, 12, NB), 256, 0, stream>>>(x, ln1_w, ln1_b, stats, xn, hn);
  // proj_in: M=32768, K=384, O=768 (128x128 tile)
  k_mfma<0><<<dim3(256, 6), 256, 0, stream>>>(hn, piw_b, proj_in_b, fus, nullptr, 0,
                                              nullptr, nullptr, 0, 384, 768, 768);
  // depthwise 7x7 (R8 proven form), then y0
  k_dwconv<<<dim3(8, 12, NB), 256, 0, stream>>>(fus, dw_w, dw_b, dw);
  k_y0<<<(MTOT * 32) / 256, 256, 0, stream>>>(fus, dw, y0);
  // pw chain (128x64 tiles for small N)
  k_mfma64<1><<<dim3(256, 1), 256, 0, stream>>>(y0, pw0b, pw0_b, y1, dw, 24, nullptr,
                                                nullptr, 0, 32, 48, 64);
  k_mfma64<1><<<dim3(256, 2), 256, 0, stream>>>(y1, pw1b, pw1_b, y2, dw, 72, nullptr,
                                                nullptr, 0, 64, 96, 96);
  k_mfma64<1><<<dim3(256, 3), 256, 0, stream>>>(y2, pw2b, pw2_b, y3, dw, 168, nullptr,
                                                nullptr, 0, 96, 192, 192);
  k_mfma64<1><<<dim3(256, 6), 256, 0, stream>>>(y3, pw3b, pw3_b, y4, dw, 360, nullptr,
                                                nullptr, 0, 192, 384, 384);
  // proj_out + gamma1 residual -> xmid (bf16), 128x64 tile
  k_mfma64<2><<<dim3(256, 6), 256, 0, stream>>>(y4, pow_b, proj_out_b, xmid, nullptr, 0,
                                                xn, gamma1, 0, 384, 384, 384);
  k_ln2<<<MTOT / 4, 256, 0, stream>>>(xmid, ln2_w, ln2_b, ln2h);
  k_cvtwL<<<4608, 256, 0, stream>>>(fc1_w, fc2_w, fc1b);
  // MLP in 2 chunks of 16 batches
  for (int ch = 0; ch < 2; ch++) {
    int m_base = ch * 16384;
    k_mfma<3><<<dim3(128, 12), 256, 0, stream>>>(ln2h + (size_t)m_base * CDIM, fc1b,
                                                 fc1_b, h1, nullptr, 0, nullptr, nullptr,
                                                 0, 384, 1536, 1536);
    k_mfma64<4><<<dim3(128, 6), 256, 0, stream>>>(h1, fc2b, fc2_b, out, nullptr, 0, xmid,
                                                  gamma2, m_base, 1536, 384, 384);
  }
}